// Round 8
// baseline (208.320 us; speedup 1.0000x reference)
//
#include <hip/hip_runtime.h>
#include <hip/hip_bf16.h>
#include <stdint.h>

#define L1DIM  1536
#define NOUT   144          // 128 (W1) + 16 (Wf) layer-1 outputs
#define NSPLIT 2            // K splits of 768
#define KSPL   768
#define CHUNK  256          // floats per row per A-chunk (1 KB)
#define NCHNK  3            // chunks per split
#define STEPS  24           // K=32 MFMA steps per split
#define LROW   260          // padded row length in floats (breaks 256-stride conflicts)
#define ROWS   16384
#define PCOLS  32           // partial cols kept per row (bucket 16 + shared 16)

typedef __bf16 bf16;
typedef __bf16 bf16x8 __attribute__((ext_vector_type(8)));
typedef float  floatx4 __attribute__((ext_vector_type(4)));

// ---------------------------------------------------------------------------
// Pack [W1;Wf] (144 x 1536 fp32) -> bf16 in MFMA B-fragment order:
//   pw[(k/8)*144 + n][0..7]  (16 B per (k-octet, feature)).
// ---------------------------------------------------------------------------
__global__ void pack_weights(const float* __restrict__ W1,
                             const float* __restrict__ Wf,
                             bf16* __restrict__ pw) {
    int t = blockIdx.x * blockDim.x + threadIdx.x;   // 0 .. 144*192-1
    if (t >= NOUT * 192) return;
    int n = t / 192;         // output feature 0..143
    int o = t % 192;         // k-octet 0..191 (consecutive per lane -> coalesced)
    const float* src = (n < 128) ? (W1 + (size_t)n * L1DIM + o * 8)
                                 : (Wf + (size_t)(n - 128) * L1DIM + o * 8);
    float4 s0 = ((const float4*)src)[0];
    float4 s1 = ((const float4*)src)[1];
    bf16x8 v;
    v[0] = (bf16)s0.x; v[1] = (bf16)s0.y; v[2] = (bf16)s0.z; v[3] = (bf16)s0.w;
    v[4] = (bf16)s1.x; v[5] = (bf16)s1.y; v[6] = (bf16)s1.z; v[7] = (bf16)s1.w;
    *(bf16x8*)(pw + ((size_t)o * NOUT + n) * 8) = v;
}

__device__ __forceinline__ bf16x8 cvt8(float4 a, float4 b) {
    bf16x8 r;
    r[0] = (bf16)a.x; r[1] = (bf16)a.y; r[2] = (bf16)a.z; r[3] = (bf16)a.w;
    r[4] = (bf16)b.x; r[5] = (bf16)b.y; r[6] = (bf16)b.z; r[7] = (bf16)b.w;
    return r;
}

// ---------------------------------------------------------------------------
// Layer-1 GEMM, ZERO barriers in/after the K-loop, all global access
// wave-contiguous.
// Grid = 2 K-splits x 128 row-blocks = 256 (1 block/CU, balanced); 512 thr.
// Each wave privately owns 16 rows x K=768: A staged into a wave-private
// padded LDS region in K=256 chunks (per row: one float4/lane = 1 KB
// contiguous load, issued a full chunk ahead; compiler tracks load->ds_write
// ->ds_read deps with fine-grained waitcnts -- no vmcnt(0) drains).
// B fragments stream directly from L2-resident pw (16 B/lane contiguous per
// 16-lane group), prefetched one K-step ahead. No __syncthreads anywhere.
// ---------------------------------------------------------------------------
__global__ __launch_bounds__(512, 2) void gemm_l1(
    const float* __restrict__ x, const int* __restrict__ lsidx,
    const bf16* __restrict__ pw, float* __restrict__ pt)
{
    __shared__ float law[8][16][LROW];   // 133120 B, wave-private slices

    const int tid  = threadIdx.x;
    const int wv   = tid >> 6;
    const int ln   = tid & 63;
    const int quad = ln >> 4;
    const int lm   = ln & 15;

    const int q   = blockIdx.x >> 7;     // K-split 0..1
    const int blk = blockIdx.x & 127;    // row block
    const int rA  = blk * 128 + wv * 16; // this wave's 16 rows

    const float* xbase = x + (size_t)rA * L1DIM + q * KSPL;
    float* lw = &law[wv][0][0];

    // ---- prologue: stage chunk 0 (16 rows x 1 KB, wave-contiguous) ----
    {
        float4 av[16];
#pragma unroll
        for (int r = 0; r < 16; r++)
            av[r] = *(const float4*)(xbase + (size_t)r * L1DIM + ln * 4);
#pragma unroll
        for (int r = 0; r < 16; r++)
            *(float4*)(lw + r * LROW + ln * 4) = av[r];
    }

    floatx4 acc[9];
#pragma unroll
    for (int i = 0; i < 9; i++) acc[i] = (floatx4){0.f, 0.f, 0.f, 0.f};

    // ---- B fragment pointers: octet = q*96 + step*4 + quad, feature t*16+lm
    const bf16* pb0 = pw + (((size_t)q * 96 + quad) * NOUT + lm) * 8;
    bf16x8 bcur[9];
#pragma unroll
    for (int t = 0; t < 9; t++)
        bcur[t] = *(const bf16x8*)(pb0 + t * 16 * 8);

    for (int c = 0; c < NCHNK; c++) {
        // ---- issue next A-chunk loads a full chunk ahead ----
        float4 av2[16];
        if (c < NCHNK - 1) {
#pragma unroll
            for (int r = 0; r < 16; r++)
                av2[r] = *(const float4*)(xbase + (size_t)r * L1DIM
                                          + (c + 1) * CHUNK + ln * 4);
        }
#pragma unroll
        for (int s = 0; s < 8; s++) {
            const int st = c * 8 + s;
            // prefetch next step's B fragments
            bf16x8 bnxt[9];
            if (st < STEPS - 1) {
                const bf16* pn = pw + (((size_t)q * 96 + (st + 1) * 4 + quad) * NOUT + lm) * 8;
#pragma unroll
                for (int t = 0; t < 9; t++)
                    bnxt[t] = *(const bf16x8*)(pn + t * 16 * 8);
            }
            // A fragment from wave-private LDS (2-way bank aliasing = free)
            const float* ap = lw + lm * LROW + s * 32 + quad * 8;
            float4 a0 = *(const float4*)ap;
            float4 a1 = *(const float4*)(ap + 4);
            bf16x8 af = cvt8(a0, a1);
#pragma unroll
            for (int t = 0; t < 9; t++)
                acc[t] = __builtin_amdgcn_mfma_f32_16x16x32_bf16(af, bcur[t], acc[t], 0, 0, 0);
            if (st < STEPS - 1) {
#pragma unroll
                for (int t = 0; t < 9; t++) bcur[t] = bnxt[t];
            }
        }
        // ---- commit next chunk to LDS (auto-ordered after this chunk's reads) ----
        if (c < NCHNK - 1) {
#pragma unroll
            for (int r = 0; r < 16; r++)
                *(float4*)(lw + r * LROW + ln * 4) = av2[r];
        }
    }

    // ---- bucket-gather & store partials: pt[q][row][0..15]=bucket, [16..31]=Wf ----
#pragma unroll
    for (int rp = 0; rp < 4; rp++) {
        const int row = rA + quad * 4 + rp;       // MFMA C layout: row=quad*4+reg
        const int bkt = lsidx[row];
        float csel = acc[0][rp];
#pragma unroll
        for (int t = 1; t < 8; t++) csel = (bkt == t) ? acc[t][rp] : csel;
        float* dst = pt + ((size_t)q * ROWS + row) * PCOLS;
        dst[lm]      = csel;
        dst[16 + lm] = acc[8][rp];
    }
}

// ---------------------------------------------------------------------------
// Epilogue: sum the 2 K-split partials, add biases, layers 2+3.
// 256 threads = 32 rows x 8 threads.
// ---------------------------------------------------------------------------
__global__ __launch_bounds__(256) void epilogue(
    const float* __restrict__ pt, const int* __restrict__ lsidx,
    const float* __restrict__ b1, const float* __restrict__ bf_,
    const float* __restrict__ W2, const float* __restrict__ b2,
    const float* __restrict__ Wo, const float* __restrict__ bo,
    float* __restrict__ out)
{
    __shared__ float ep[32][33];

    const int tid = threadIdx.x;
    const int er  = tid >> 3;           // row in block, 0..31
    const int sub = tid & 7;            // 0..7
    const int row = blockIdx.x * 32 + er;

    float4 s = {0.f, 0.f, 0.f, 0.f};
#pragma unroll
    for (int q = 0; q < NSPLIT; q++) {
        float4 v = *(const float4*)&pt[((size_t)q * ROWS + row) * PCOLS + sub * 4];
        s.x += v.x; s.y += v.y; s.z += v.z; s.w += v.w;
    }
    *(float4*)&ep[er][sub * 4] = s;
    __syncthreads();

    const int bkt = lsidx[row];
    const float l1c15 = ep[er][15] + b1[bkt * 16 + 15];
    const float l1f15 = ep[er][31] + bf_[15];

    float l1x[30];
#pragma unroll
    for (int j = 0; j < 15; j++) {
        float tj = (ep[er][j] + b1[bkt * 16 + j]) + (ep[er][16 + j] + bf_[j]);
        float sq = tj * tj * (127.0f / 128.0f);
        l1x[j]      = fminf(fmaxf(sq, 0.f), 1.f);
        l1x[15 + j] = fminf(fmaxf(tj, 0.f), 1.f);
    }

    float part = 0.f;
#pragma unroll
    for (int o = 0; o < 8; o++) {
        const int oi = bkt * 64 + sub * 8 + o;
        const float2* wrow = (const float2*)(W2 + oi * 30);   // 8B-aligned
        float a = b2[oi];
#pragma unroll
        for (int j2 = 0; j2 < 15; j2++) {
            float2 w = wrow[j2];
            a += l1x[2 * j2] * w.x + l1x[2 * j2 + 1] * w.y;
        }
        a = fminf(fmaxf(a, 0.f), 1.f);
        part += a * Wo[oi];
    }
    part += __shfl_xor(part, 1);
    part += __shfl_xor(part, 2);
    part += __shfl_xor(part, 4);
    if (sub == 0) out[row] = part + bo[bkt] + l1c15 + l1f15;
}

extern "C" void kernel_launch(void* const* d_in, const int* in_sizes, int n_in,
                              void* d_out, int out_size, void* d_ws, size_t ws_size,
                              hipStream_t stream) {
    const float* x   = (const float*)d_in[0];
    const int*   idx = (const int*)  d_in[1];
    const float* W1  = (const float*)d_in[2];
    const float* b1  = (const float*)d_in[3];
    const float* Wf  = (const float*)d_in[4];
    const float* bf  = (const float*)d_in[5];
    const float* W2  = (const float*)d_in[6];
    const float* b2  = (const float*)d_in[7];
    const float* Wo  = (const float*)d_in[8];
    const float* bo  = (const float*)d_in[9];
    float* out = (float*)d_out;

    // ws layout: pt (2*16384*32*4 = 4 MB) | pw (442368 B)
    float* pt = (float*)d_ws;
    bf16*  pw = (bf16*)((char*)d_ws + (size_t)NSPLIT * ROWS * PCOLS * 4);

    pack_weights<<<dim3((NOUT * 192 + 255) / 256), dim3(256), 0, stream>>>(W1, Wf, pw);
    gemm_l1<<<dim3(NSPLIT * 128), dim3(512), 0, stream>>>(x, idx, pw, pt);
    epilogue<<<dim3(ROWS / 32), dim3(256), 0, stream>>>(pt, idx, b1, bf, W2, b2, Wo, bo, out);
}

// Round 9
// 185.635 us; speedup vs baseline: 1.1222x; 1.1222x over previous
//
#include <hip/hip_runtime.h>
#include <hip/hip_bf16.h>
#include <stdint.h>

#define L1DIM  1536
#define NOUT   144          // 128 (W1) + 16 (Wf) layer-1 outputs
#define NSPLIT 2            // K splits of 768
#define KSPL   768
#define CHUNK  128          // floats per row per A-chunk (512 B)
#define CSTEPS 4            // K=32 MFMA steps per chunk
#define NCHNK  6            // chunks per split
#define STEPS  24           // K=32 MFMA steps per split
#define LROWF  132          // floats per LDS row buffer (528 B: 512 + 16 pad)
#define ROWS   16384
#define PCOLS  32           // partial cols kept per row (bucket 16 + shared 16)

typedef __bf16 bf16;
typedef __bf16 bf16x8 __attribute__((ext_vector_type(8)));
typedef float  floatx4 __attribute__((ext_vector_type(4)));

// ---------------------------------------------------------------------------
// Pack [W1;Wf] (144 x 1536 fp32) -> bf16 in MFMA B-fragment order:
//   pw[(k/8)*144 + n][0..7]  (16 B per (k-octet, feature)).
// ---------------------------------------------------------------------------
__global__ void pack_weights(const float* __restrict__ W1,
                             const float* __restrict__ Wf,
                             bf16* __restrict__ pw) {
    int t = blockIdx.x * blockDim.x + threadIdx.x;   // 0 .. 144*192-1
    if (t >= NOUT * 192) return;
    int n = t / 192;         // output feature 0..143
    int o = t % 192;         // k-octet 0..191 (consecutive per lane -> coalesced)
    const float* src = (n < 128) ? (W1 + (size_t)n * L1DIM + o * 8)
                                 : (Wf + (size_t)(n - 128) * L1DIM + o * 8);
    float4 s0 = ((const float4*)src)[0];
    float4 s1 = ((const float4*)src)[1];
    bf16x8 v;
    v[0] = (bf16)s0.x; v[1] = (bf16)s0.y; v[2] = (bf16)s0.z; v[3] = (bf16)s0.w;
    v[4] = (bf16)s1.x; v[5] = (bf16)s1.y; v[6] = (bf16)s1.z; v[7] = (bf16)s1.w;
    *(bf16x8*)(pw + ((size_t)o * NOUT + n) * 8) = v;
}

__device__ __forceinline__ void gload_lds16(const void* g, void* l) {
    __builtin_amdgcn_global_load_lds(
        (const __attribute__((address_space(1))) void*)g,
        (__attribute__((address_space(3))) void*)l, 16, 0, 0);
}

__device__ __forceinline__ bf16x8 cvt8(float4 a, float4 b) {
    bf16x8 r;
    r[0] = (bf16)a.x; r[1] = (bf16)a.y; r[2] = (bf16)a.z; r[3] = (bf16)a.w;
    r[4] = (bf16)b.x; r[5] = (bf16)b.y; r[6] = (bf16)b.z; r[7] = (bf16)b.w;
    return r;
}

// ---------------------------------------------------------------------------
// Layer-1 GEMM. Barrier-free, wave-contiguous, ZERO register staging:
//  - A staged HBM->LDS via global_load_lds (no VGPR roundtrip, no spill):
//    per chunk 16 instrs (one per row, half-wave exec-masked, 512 B each),
//    double-buffered per-wave; per-wave s_waitcnt vmcnt(0) at chunk bounds
//    (NO s_barrier -> waves stagger, HBM streams continuously).
//  - B fragments stream from L2/L1-resident pw, 1-step register prefetch.
// Grid = 2 K-splits x 128 row-blocks = 256 (1 block/CU, balanced); 512 thr;
// each wave owns 16 rows x K=768. LDS 8 waves x 2 x 16 x 528 B = 135168 B.
// ---------------------------------------------------------------------------
__global__ __launch_bounds__(512, 2) void gemm_l1(
    const float* __restrict__ x, const int* __restrict__ lsidx,
    const bf16* __restrict__ pw, float* __restrict__ pt)
{
    __shared__ float law[8][2][16][LROWF];   // 135168 B, wave-private slices

    const int tid  = threadIdx.x;
    const int wv   = tid >> 6;
    const int ln   = tid & 63;
    const int quad = ln >> 4;
    const int lm   = ln & 15;

    const int q   = blockIdx.x >> 7;     // K-split 0..1
    const int blk = blockIdx.x & 127;    // row block
    const int rA  = blk * 128 + wv * 16; // this wave's 16 rows

    const float* xbase = x + (size_t)rA * L1DIM + q * KSPL;

    // ---- A staging: chunk c -> buffer buf (16 rows x 512 B, lanes 0-31) ----
    auto stageA = [&](int buf, int c) {
        if (ln < 32) {
            const float* g = xbase + c * CHUNK + ln * 4;      // lane: 16 B
            float* l = &law[wv][buf][0][0] + ln * 4;
#pragma unroll
            for (int r = 0; r < 16; r++)
                gload_lds16(g + (size_t)r * L1DIM, l + r * LROWF);
        }
    };

    // ---- B fragment load for step st (octet q*96 + st*4 + quad) ----
    auto loadB = [&](int st, bf16x8* dst) {
        const bf16* p = pw + (((size_t)q * 96 + st * 4 + quad) * NOUT + lm) * 8;
#pragma unroll
        for (int t = 0; t < 9; t++)
            dst[t] = *(const bf16x8*)(p + (size_t)t * 16 * 8);
    };

    floatx4 acc[9];
#pragma unroll
    for (int i = 0; i < 9; i++) acc[i] = (floatx4){0.f, 0.f, 0.f, 0.f};

    stageA(0, 0);
    asm volatile("s_waitcnt vmcnt(0)" ::: "memory");

    bf16x8 bcur[9];
    loadB(0, bcur);

    for (int c = 0; c < NCHNK; c++) {
        if (c < NCHNK - 1) stageA((c + 1) & 1, c + 1);   // overlaps this chunk's compute
#pragma unroll
        for (int s = 0; s < CSTEPS; s++) {
            const int st = c * CSTEPS + s;
            bf16x8 bnxt[9];
            if (st < STEPS - 1) loadB(st + 1, bnxt);
            const float* ap = &law[wv][c & 1][lm][s * 32 + quad * 8];
            float4 a0 = *(const float4*)ap;
            float4 a1 = *(const float4*)(ap + 4);
            bf16x8 af = cvt8(a0, a1);
#pragma unroll
            for (int t = 0; t < 9; t++)
                acc[t] = __builtin_amdgcn_mfma_f32_16x16x32_bf16(af, bcur[t], acc[t], 0, 0, 0);
            if (st < STEPS - 1) {
#pragma unroll
                for (int t = 0; t < 9; t++) bcur[t] = bnxt[t];
            }
        }
        // per-wave drain of next chunk's staging (no barrier; waves stagger)
        asm volatile("s_waitcnt vmcnt(0)" ::: "memory");
    }

    // ---- bucket-gather & store partials: pt[q][row][0..15]=bucket, [16..31]=Wf ----
#pragma unroll
    for (int rp = 0; rp < 4; rp++) {
        const int row = rA + quad * 4 + rp;       // MFMA C layout: row=quad*4+reg
        const int bkt = lsidx[row];
        float csel = acc[0][rp];
#pragma unroll
        for (int t = 1; t < 8; t++) csel = (bkt == t) ? acc[t][rp] : csel;
        float* dst = pt + ((size_t)q * ROWS + row) * PCOLS;
        dst[lm]      = csel;
        dst[16 + lm] = acc[8][rp];
    }
}

// ---------------------------------------------------------------------------
// Epilogue: sum the 2 K-split partials, add biases, layers 2+3.
// 256 threads = 32 rows x 8 threads.
// ---------------------------------------------------------------------------
__global__ __launch_bounds__(256) void epilogue(
    const float* __restrict__ pt, const int* __restrict__ lsidx,
    const float* __restrict__ b1, const float* __restrict__ bf_,
    const float* __restrict__ W2, const float* __restrict__ b2,
    const float* __restrict__ Wo, const float* __restrict__ bo,
    float* __restrict__ out)
{
    __shared__ float ep[32][33];

    const int tid = threadIdx.x;
    const int er  = tid >> 3;           // row in block, 0..31
    const int sub = tid & 7;            // 0..7
    const int row = blockIdx.x * 32 + er;

    float4 s = {0.f, 0.f, 0.f, 0.f};
#pragma unroll
    for (int q = 0; q < NSPLIT; q++) {
        float4 v = *(const float4*)&pt[((size_t)q * ROWS + row) * PCOLS + sub * 4];
        s.x += v.x; s.y += v.y; s.z += v.z; s.w += v.w;
    }
    *(float4*)&ep[er][sub * 4] = s;
    __syncthreads();

    const int bkt = lsidx[row];
    const float l1c15 = ep[er][15] + b1[bkt * 16 + 15];
    const float l1f15 = ep[er][31] + bf_[15];

    float l1x[30];
#pragma unroll
    for (int j = 0; j < 15; j++) {
        float tj = (ep[er][j] + b1[bkt * 16 + j]) + (ep[er][16 + j] + bf_[j]);
        float sq = tj * tj * (127.0f / 128.0f);
        l1x[j]      = fminf(fmaxf(sq, 0.f), 1.f);
        l1x[15 + j] = fminf(fmaxf(tj, 0.f), 1.f);
    }

    float part = 0.f;
#pragma unroll
    for (int o = 0; o < 8; o++) {
        const int oi = bkt * 64 + sub * 8 + o;
        const float2* wrow = (const float2*)(W2 + oi * 30);   // 8B-aligned
        float a = b2[oi];
#pragma unroll
        for (int j2 = 0; j2 < 15; j2++) {
            float2 w = wrow[j2];
            a += l1x[2 * j2] * w.x + l1x[2 * j2 + 1] * w.y;
        }
        a = fminf(fmaxf(a, 0.f), 1.f);
        part += a * Wo[oi];
    }
    part += __shfl_xor(part, 1);
    part += __shfl_xor(part, 2);
    part += __shfl_xor(part, 4);
    if (sub == 0) out[row] = part + bo[bkt] + l1c15 + l1f15;
}

extern "C" void kernel_launch(void* const* d_in, const int* in_sizes, int n_in,
                              void* d_out, int out_size, void* d_ws, size_t ws_size,
                              hipStream_t stream) {
    const float* x   = (const float*)d_in[0];
    const int*   idx = (const int*)  d_in[1];
    const float* W1  = (const float*)d_in[2];
    const float* b1  = (const float*)d_in[3];
    const float* Wf  = (const float*)d_in[4];
    const float* bf  = (const float*)d_in[5];
    const float* W2  = (const float*)d_in[6];
    const float* b2  = (const float*)d_in[7];
    const float* Wo  = (const float*)d_in[8];
    const float* bo  = (const float*)d_in[9];
    float* out = (float*)d_out;

    // ws layout: pt (2*16384*32*4 = 4 MB) | pw (442368 B)
    float* pt = (float*)d_ws;
    bf16*  pw = (bf16*)((char*)d_ws + (size_t)NSPLIT * ROWS * PCOLS * 4);

    pack_weights<<<dim3((NOUT * 192 + 255) / 256), dim3(256), 0, stream>>>(W1, Wf, pw);
    gemm_l1<<<dim3(NSPLIT * 128), dim3(512), 0, stream>>>(x, idx, pw, pt);
    epilogue<<<dim3(ROWS / 32), dim3(256), 0, stream>>>(pt, idx, b1, bf, W2, b2, Wo, bo, out);
}